// Round 5
// baseline (632.130 us; speedup 1.0000x reference)
//
#include <hip/hip_runtime.h>

#define Mdim 4096
#define Kdim 4096
#define Ndim 12288

typedef __bf16 bf16x8 __attribute__((ext_vector_type(8)));
typedef float f32x4 __attribute__((ext_vector_type(4)));
typedef unsigned short u16x8 __attribute__((ext_vector_type(8)));
typedef int i32x4 __attribute__((ext_vector_type(4)));

__device__ __forceinline__ unsigned short f2bf(float f) {
    unsigned int u = __builtin_bit_cast(unsigned int, f);
    u += 0x7FFFu + ((u >> 16) & 1u);       // RNE
    return (unsigned short)(u >> 16);
}

typedef __attribute__((address_space(1))) void gvoid_t;
typedef __attribute__((address_space(3))) void lvoid_t;
__device__ __forceinline__ void gld16(const void* g, void* l) {
    // 16B per lane, LDS dest = wave-uniform base + lane*16
    __builtin_amdgcn_global_load_lds((gvoid_t*)g, (lvoid_t*)l, 16, 0, 0);
}

// ---------------------------------------------------------------------------
// TILED OPERAND FORMAT (fragment order), shared by writer kernels and GEMM.
// For a 256-row operand tile bx (bm or bn), element (row, k):
//   ks = k>>5 (region, 8192 halves), kk = k&31, q = row>>4 (512-half block),
//   chunk l = (row&15) + 16*(kk>>3)   (16B chunks, MFMA-fragment order)
//   addr_halves = bx*2^20 + ks*8192 + q*512 + l*8 + (kk&7)
// GEMM staging reads 1KB fully-contiguous per wave-instr AND the LDS image
// gives fully-sequential fragment ds_reads (0 bank conflicts, r4-verified).
// ---------------------------------------------------------------------------

// ---------------------------------------------------------------------------
// Kernel 0: A fp32 -> bf16, K-permutation folded in, TILED output (unchanged).
// ---------------------------------------------------------------------------
__global__ __launch_bounds__(512) void permute_convert_a_kernel(
    const float* __restrict__ A, const int* __restrict__ invperm,
    unsigned short* __restrict__ Ab)
{
    __shared__ unsigned short rowbuf[16][4104];   // +16B row pad (bank spread)
    const int tid = threadIdx.x;
    const int m0 = blockIdx.x * 16;
    const int bm = m0 >> 8;
    const int q  = (m0 >> 4) & 15;
#pragma unroll
    for (int c = 0; c < 2; ++c) {
        const int i = (c * 512 + tid) * 4;
        const i32x4 ip = *(const i32x4*)&invperm[i];
        for (int r = 0; r < 16; ++r) {
            const f32x4 v = *(const f32x4*)&A[(size_t)(m0 + r) * Kdim + i];
#pragma unroll
            for (int u = 0; u < 4; ++u) rowbuf[r][ip[u]] = f2bf(v[u]);
        }
    }
    __syncthreads();
    unsigned short* dst = Ab + ((size_t)bm << 20) + q * 512;
    for (int it = 0; it < 16; ++it) {
        const int c = it * 512 + tid;             // 0..8191
        const int ks = c >> 6, c8 = c & 63;
        const u16x8 v = *(const u16x8*)&rowbuf[c8 & 15][ks * 32 + (c8 >> 4) * 8];
        *(u16x8*)&dst[(size_t)ks * 8192 + c8 * 8] = v;   // 1KB contig / 64 thr
    }
}

// ---------------------------------------------------------------------------
// Kernel 1: dequant in natural k-order, TILED output (unchanged).
// ---------------------------------------------------------------------------
__global__ __launch_bounds__(256) void dequant_kernel(
    const int* __restrict__ qw,              // [K/8][N]
    const int* __restrict__ qs,              // [G][N/8]
    const float* __restrict__ qsm,           // [G] fp32
    unsigned short* __restrict__ Wt)         // tiled bf16 bits
{
    __shared__ unsigned short tile[64 * 72];
    const int k0 = blockIdx.x * 64;
    const int n0 = blockIdx.y * 64;
    const int g = k0 >> 7;
    const int tid = threadIdx.x;
    const int n_l = tid & 63;
    const int kb_l = tid >> 6;
    const int n = n0 + n_l;
    const int sw = qs[g * (Ndim / 8) + (n >> 3)];
    const int sc = (sw >> ((n & 7) * 4)) & 0xF;
    const float scale = (float)((sc + 1) * (sc + 1)) * qsm[g];
#pragma unroll
    for (int ii = 0; ii < 2; ++ii) {
        const int kb = kb_l + ii * 4;
        const int w = qw[(size_t)(k0 / 8 + kb) * Ndim + n];
        u16x8 o;
#pragma unroll
        for (int u = 0; u < 8; ++u)
            o[u] = f2bf((float)(((w >> (4 * u)) & 0xF) - 8) * scale);
        *(u16x8*)&tile[n_l * 72 + kb * 8] = o;
    }
    __syncthreads();
    const int bn  = n0 >> 8;
    const int q0  = (n0 >> 4) & 15;
    const int ks0 = k0 >> 5;
    unsigned short* dst = Wt + ((size_t)bn << 20) + (size_t)ks0 * 8192 + q0 * 512;
#pragma unroll
    for (int cc = 0; cc < 2; ++cc) {
        const int c  = cc * 256 + tid;            // 0..511
        const int ksl = c >> 8;                   // 0..1
        const int cq  = (c >> 6) & 3;             // q-block within our 64n
        const int c8  = c & 63;
        const u16x8 v = *(const u16x8*)
            &tile[(cq * 16 + (c8 & 15)) * 72 + ksl * 32 + (c8 >> 4) * 8];
        *(u16x8*)&dst[(size_t)ksl * 8192 + cq * 512 + c8 * 8] = v;
    }
}

// ---------------------------------------------------------------------------
// Kernel 2: bf16 GEMM, 256x256 tile, BK=64, 8 waves, pre-tiled operands.
// NEW (round 5): 2 barriers per K-TILE (was 8).  The whole tile's 24
// ds_read_b128 + 64 MFMA live in ONE inter-barrier region: waves desync, so
// LDS-pipe reads of one wave overlap MFMA of another (m114 co-scheduling);
// compiler's fine lgkmcnt pipelines each wave's own reads into its MFMAs.
// Hazards (4-slot ring, re-derived):
//   bar A: all waves done reading tile t-1's slots -> safe to STAGE regions
//     2t+2,2t+3 (their slots = t+1's read slots, disjoint from t's).
//   vmcnt(8) BEFORE bar B: retires this wave's previous-tile stages
//     (regions 2t,2t+1); after bar B every wave's stages are in LDS.
//   Tail: t=63 stages nothing, drains with vmcnt(0) (t=62 staged 126,127).
// Reads can be freely reordered by the compiler within the region (all read
// slots valid throughout).  MFMA hoist-past-barrier is impossible: af/bf are
// data-dependent on ds_reads that the "memory" clobber pins below bar B.
// ---------------------------------------------------------------------------
#define BAR()    asm volatile("s_barrier" ::: "memory")
#define VMCNT8() asm volatile("s_waitcnt vmcnt(8)" ::: "memory")
#define VMCNT0() asm volatile("s_waitcnt vmcnt(0)" ::: "memory")

#define STAGE(dstW, src, slot, R) do {                                      \
    gld16((src) + (size_t)(R) * 8192, (dstW) + (slot) * 8192);              \
    gld16((src) + (size_t)(R) * 8192 + 4096,                                \
          (dstW) + (slot) * 8192 + 4096); } while (0)

#define LD_A(slot, mh) do {                                                 \
    const unsigned short* p_ = &As[slot][wm * 4096 + (mh) * 2048 + aOff];   \
    af[0] = *(const bf16x8*)(p_);                                           \
    af[1] = *(const bf16x8*)(p_ + 512);                                     \
    af[2] = *(const bf16x8*)(p_ + 1024);                                    \
    af[3] = *(const bf16x8*)(p_ + 1536); } while (0)

#define LD_B(slot) do {                                                     \
    const unsigned short* p_ = &Bs[slot][wn * 2048 + aOff];                 \
    bf[0] = *(const bf16x8*)(p_);                                           \
    bf[1] = *(const bf16x8*)(p_ + 512);                                     \
    bf[2] = *(const bf16x8*)(p_ + 1024);                                    \
    bf[3] = *(const bf16x8*)(p_ + 1536); } while (0)

#define MFMA_HALF(mh) do {                                                  \
    __builtin_amdgcn_s_setprio(1);                                          \
    _Pragma("unroll")                                                       \
    for (int i_ = 0; i_ < 4; ++i_)                                          \
      _Pragma("unroll")                                                     \
      for (int j_ = 0; j_ < 4; ++j_)                                        \
        acc[(mh) * 4 + i_][j_] = __builtin_amdgcn_mfma_f32_16x16x32_bf16(   \
            af[i_], bf[j_], acc[(mh) * 4 + i_][j_], 0, 0, 0);               \
    __builtin_amdgcn_s_setprio(0); } while (0)

__global__ __launch_bounds__(512, 2) void gemm_bf16_256_kernel(
    const unsigned short* __restrict__ A,    // tiled [M-tiles] bf16 bits
    const unsigned short* __restrict__ Bt,   // tiled [N-tiles] bf16 bits
    const float* __restrict__ bias,          // [N] fp32
    float* __restrict__ C)                   // [M][N] fp32
{
    __shared__ __attribute__((aligned(16))) unsigned short As[4][8192];
    __shared__ __attribute__((aligned(16))) unsigned short Bs[4][8192];

    const int tid = threadIdx.x;
    const int lane = tid & 63, wave = tid >> 6;
    const int wm = wave >> 2, wn = wave & 3;

    // bijective XCD swizzle: 768 wgs = 8 XCDs x 96.
    const int wgid = (blockIdx.x & 7) * 96 + (blockIdx.x >> 3);
    const int bm = wgid & 15;    // 0..15  (M/256)
    const int bn = wgid >> 4;    // 0..47  (N/256)

    // ---- staging: pure linear stream; thread t covers bytes t*16 ----
    const unsigned short* Ag = A + ((size_t)bm << 20) + tid * 8;
    const unsigned short* Bg = Bt + ((size_t)bn << 20) + tid * 8;
    unsigned short* AsW = &As[0][0] + wave * 512;   // wave-uniform dest base
    unsigned short* BsW = &Bs[0][0] + wave * 512;

    // ---- fragment read offset: contiguous, lane*16B within q-block ----
    const int aOff = lane * 8;

    f32x4 acc[8][4];
    const f32x4 zero = {0.f, 0.f, 0.f, 0.f};
#pragma unroll
    for (int i = 0; i < 8; ++i)
#pragma unroll
        for (int j = 0; j < 4; ++j) acc[i][j] = zero;

    // ---- prologue: stage regions 0,1 (8 glds outstanding) ----
    STAGE(AsW, Ag, 0, 0);
    STAGE(BsW, Bg, 0, 0);
    STAGE(AsW, Ag, 1, 1);
    STAGE(BsW, Bg, 1, 1);

    bf16x8 af[4], bf[4];
#pragma unroll 2
    for (int t = 0; t < 64; ++t) {
        const int s0 = (2 * t) & 3, s1 = (2 * t + 1) & 3;
        const int sA = (2 * t + 2) & 3, sB = (2 * t + 3) & 3;

        BAR();                          // bar A: prev tile's ds_reads done
        if (t < 63) {
            STAGE(AsW, Ag, sA, 2 * t + 2);
            STAGE(BsW, Bg, sA, 2 * t + 2);
            STAGE(AsW, Ag, sB, 2 * t + 3);
            STAGE(BsW, Bg, sB, 2 * t + 3);
            VMCNT8();                   // retires regions 2t, 2t+1 (ours)
        } else {
            VMCNT0();                   // tail: drain regions 126,127
        }
        BAR();                          // bar B: all waves' stages in LDS

        // one region: 24 ds_read_b128 + 64 MFMA, compiler-pipelined,
        // waves desynchronized -> LDS pipe overlaps MFMA pipe.
        LD_A(s0, 0);
        LD_B(s0);
        MFMA_HALF(0);
        LD_A(s0, 1);
        MFMA_HALF(1);
        LD_A(s1, 0);
        LD_B(s1);
        MFMA_HALF(0);
        LD_A(s1, 1);
        MFMA_HALF(1);
    }

    // ---- epilogue: C/D layout col = lane&15, row = (lane>>4)*4 + r ----
    const int colb = bn * 256 + wn * 64 + (lane & 15);
    const int rowb = bm * 256 + wm * 128 + (lane >> 4) * 4;
    float bj[4];
#pragma unroll
    for (int j = 0; j < 4; ++j) bj[j] = bias[colb + j * 16];
#pragma unroll
    for (int mf = 0; mf < 8; ++mf)
#pragma unroll
        for (int r = 0; r < 4; ++r) {
            const size_t row = (size_t)(rowb + mf * 16 + r);
#pragma unroll
            for (int j = 0; j < 4; ++j)
                C[row * Ndim + colb + j * 16] = acc[mf][j][r] + bj[j];
        }
}

extern "C" void kernel_launch(void* const* d_in, const int* in_sizes, int n_in,
                              void* d_out, int out_size, void* d_ws, size_t ws_size,
                              hipStream_t stream) {
    const float* input   = (const float*)d_in[0];   // [M][K] fp32 (fp16 promoted)
    const int*   qw      = (const int*)d_in[1];     // [K/8][N]
    const int*   qs      = (const int*)d_in[2];     // [G][N/8]
    const float* qsm     = (const float*)d_in[3];   // [G] fp32
    const int*   invperm = (const int*)d_in[4];     // [K]
    const float* bias    = (const float*)d_in[5];   // [N] fp32 (zeros)
    float*       out     = (float*)d_out;           // [M][N] fp32

    unsigned short* Ab = (unsigned short*)d_ws;                      // 32 MiB
    unsigned short* Wt = (unsigned short*)((char*)d_ws + ((size_t)Mdim * Kdim * 2)); // 96 MiB

    permute_convert_a_kernel<<<Mdim / 16, 512, 0, stream>>>(input, invperm, Ab);
    dequant_kernel<<<dim3(Kdim / 64, Ndim / 64), 256, 0, stream>>>(qw, qs, qsm, Wt);
    gemm_bf16_256_kernel<<<dim3((Mdim / 256) * (Ndim / 256)), 512, 0, stream>>>(
        Ab, Wt, bias, out);
}

// Round 6
// 622.343 us; speedup vs baseline: 1.0157x; 1.0157x over previous
//
#include <hip/hip_runtime.h>

#define Mdim 4096
#define Kdim 4096
#define Ndim 12288

typedef __bf16 bf16x8 __attribute__((ext_vector_type(8)));
typedef float f32x4 __attribute__((ext_vector_type(4)));
typedef unsigned short u16x8 __attribute__((ext_vector_type(8)));
typedef int i32x4 __attribute__((ext_vector_type(4)));

__device__ __forceinline__ unsigned short f2bf(float f) {
    unsigned int u = __builtin_bit_cast(unsigned int, f);
    u += 0x7FFFu + ((u >> 16) & 1u);       // RNE
    return (unsigned short)(u >> 16);
}

typedef __attribute__((address_space(1))) void gvoid_t;
typedef __attribute__((address_space(3))) void lvoid_t;
__device__ __forceinline__ void gld16(const void* g, void* l) {
    // 16B per lane, LDS dest = wave-uniform base + lane*16
    __builtin_amdgcn_global_load_lds((gvoid_t*)g, (lvoid_t*)l, 16, 0, 0);
}

// ---------------------------------------------------------------------------
// TILED OPERAND FORMAT (fragment order), shared by writer kernels and GEMM.
// For a 256-row operand tile bx (bm or bn), element (row, k):
//   ks = k>>5 (region, 8192 halves), kk = k&31, q = row>>4 (512-half block),
//   chunk l = (row&15) + 16*(kk>>3)   (16B chunks, MFMA-fragment order)
//   addr_halves = bx*2^20 + ks*8192 + q*512 + l*8 + (kk&7)
// GEMM staging reads 1KB fully-contiguous per wave-instr AND the LDS image
// gives fully-sequential fragment ds_reads (0 bank conflicts, r4-verified).
// ---------------------------------------------------------------------------

// ---------------------------------------------------------------------------
// Kernel 0: A fp32 -> bf16, K-permutation folded in, TILED output (unchanged).
// ---------------------------------------------------------------------------
__global__ __launch_bounds__(512) void permute_convert_a_kernel(
    const float* __restrict__ A, const int* __restrict__ invperm,
    unsigned short* __restrict__ Ab)
{
    __shared__ unsigned short rowbuf[16][4104];   // +16B row pad (bank spread)
    const int tid = threadIdx.x;
    const int m0 = blockIdx.x * 16;
    const int bm = m0 >> 8;
    const int q  = (m0 >> 4) & 15;
#pragma unroll
    for (int c = 0; c < 2; ++c) {
        const int i = (c * 512 + tid) * 4;
        const i32x4 ip = *(const i32x4*)&invperm[i];
        for (int r = 0; r < 16; ++r) {
            const f32x4 v = *(const f32x4*)&A[(size_t)(m0 + r) * Kdim + i];
#pragma unroll
            for (int u = 0; u < 4; ++u) rowbuf[r][ip[u]] = f2bf(v[u]);
        }
    }
    __syncthreads();
    unsigned short* dst = Ab + ((size_t)bm << 20) + q * 512;
    for (int it = 0; it < 16; ++it) {
        const int c = it * 512 + tid;             // 0..8191
        const int ks = c >> 6, c8 = c & 63;
        const u16x8 v = *(const u16x8*)&rowbuf[c8 & 15][ks * 32 + (c8 >> 4) * 8];
        *(u16x8*)&dst[(size_t)ks * 8192 + c8 * 8] = v;   // 1KB contig / 64 thr
    }
}

// ---------------------------------------------------------------------------
// Kernel 1: dequant in natural k-order, TILED output (unchanged).
// ---------------------------------------------------------------------------
__global__ __launch_bounds__(256) void dequant_kernel(
    const int* __restrict__ qw,              // [K/8][N]
    const int* __restrict__ qs,              // [G][N/8]
    const float* __restrict__ qsm,           // [G] fp32
    unsigned short* __restrict__ Wt)         // tiled bf16 bits
{
    __shared__ unsigned short tile[64 * 72];
    const int k0 = blockIdx.x * 64;
    const int n0 = blockIdx.y * 64;
    const int g = k0 >> 7;
    const int tid = threadIdx.x;
    const int n_l = tid & 63;
    const int kb_l = tid >> 6;
    const int n = n0 + n_l;
    const int sw = qs[g * (Ndim / 8) + (n >> 3)];
    const int sc = (sw >> ((n & 7) * 4)) & 0xF;
    const float scale = (float)((sc + 1) * (sc + 1)) * qsm[g];
#pragma unroll
    for (int ii = 0; ii < 2; ++ii) {
        const int kb = kb_l + ii * 4;
        const int w = qw[(size_t)(k0 / 8 + kb) * Ndim + n];
        u16x8 o;
#pragma unroll
        for (int u = 0; u < 8; ++u)
            o[u] = f2bf((float)(((w >> (4 * u)) & 0xF) - 8) * scale);
        *(u16x8*)&tile[n_l * 72 + kb * 8] = o;
    }
    __syncthreads();
    const int bn  = n0 >> 8;
    const int q0  = (n0 >> 4) & 15;
    const int ks0 = k0 >> 5;
    unsigned short* dst = Wt + ((size_t)bn << 20) + (size_t)ks0 * 8192 + q0 * 512;
#pragma unroll
    for (int cc = 0; cc < 2; ++cc) {
        const int c  = cc * 256 + tid;            // 0..511
        const int ksl = c >> 8;                   // 0..1
        const int cq  = (c >> 6) & 3;             // q-block within our 64n
        const int c8  = c & 63;
        const u16x8 v = *(const u16x8*)
            &tile[(cq * 16 + (c8 & 15)) * 72 + ksl * 32 + (c8 >> 4) * 8];
        *(u16x8*)&dst[(size_t)ksl * 8192 + cq * 512 + c8 * 8] = v;
    }
}

// ---------------------------------------------------------------------------
// Kernel 2: bf16 GEMM, 256x256 tile, BK=64, 8 waves, pre-tiled operands.
// Round-4 4-phase schedule (proven 380us / 48.7% MfmaUtil) + NEW round-6
// change: one-phase REGISTER PREFETCH.  Each phase's ds_reads load the NEXT
// phase's fragments (double-buffered afX/afY, bf0/bf1), so their latency
// hides under the current 16-MFMA cluster and each MFMA cluster starts with
// its operands already resident (lgkm wait ~0).
// Slot validity at each prefetch point (vmcnt FIFO, re-derived):
//   P1 prefetch reads s0       (valid since prev-tile P4 vmcnt8)
//   P2 prefetch reads s1       (region 2t+1 retired by THIS vmcnt8)
//   P3 prefetch reads s1       (same)
//   P4 prefetch reads sA=s0'   (region 2t+2 retired by THIS vmcnt8)
// Read-vs-stage races: every STAGE targeting a slot is >=1 barrier after the
// reading wave's own lgkm drain (it must drain to reach its MFMA, which
// precedes the barrier the staging wave must pass).  Tail t=63: clamped
// redundant stages keep FIFO accounting uniform (slots they hit are dead).
// ---------------------------------------------------------------------------
#define BAR()    asm volatile("s_barrier" ::: "memory")
#define VMCNT8() asm volatile("s_waitcnt vmcnt(8)" ::: "memory")

#define STAGE(dstW, src, slot, R) do {                                      \
    gld16((src) + (size_t)(R) * 8192, (dstW) + (slot) * 8192);              \
    gld16((src) + (size_t)(R) * 8192 + 4096,                                \
          (dstW) + (slot) * 8192 + 4096); } while (0)

#define LD_A_SET(dst, slot, mh) do {                                        \
    const unsigned short* p_ = &As[slot][wm * 4096 + (mh) * 2048 + aOff];   \
    dst[0] = *(const bf16x8*)(p_);                                          \
    dst[1] = *(const bf16x8*)(p_ + 512);                                    \
    dst[2] = *(const bf16x8*)(p_ + 1024);                                   \
    dst[3] = *(const bf16x8*)(p_ + 1536); } while (0)

#define LD_B_SET(dst, slot) do {                                            \
    const unsigned short* p_ = &Bs[slot][wn * 2048 + aOff];                 \
    dst[0] = *(const bf16x8*)(p_);                                          \
    dst[1] = *(const bf16x8*)(p_ + 512);                                    \
    dst[2] = *(const bf16x8*)(p_ + 1024);                                   \
    dst[3] = *(const bf16x8*)(p_ + 1536); } while (0)

#define MFMA_SET(aset, bset, mh) do {                                       \
    __builtin_amdgcn_s_setprio(1);                                          \
    _Pragma("unroll")                                                       \
    for (int i_ = 0; i_ < 4; ++i_)                                          \
      _Pragma("unroll")                                                     \
      for (int j_ = 0; j_ < 4; ++j_)                                        \
        acc[(mh) * 4 + i_][j_] = __builtin_amdgcn_mfma_f32_16x16x32_bf16(   \
            aset[i_], bset[j_], acc[(mh) * 4 + i_][j_], 0, 0, 0);           \
    __builtin_amdgcn_s_setprio(0); } while (0)

__global__ __launch_bounds__(512, 2) void gemm_bf16_256_kernel(
    const unsigned short* __restrict__ A,    // tiled [M-tiles] bf16 bits
    const unsigned short* __restrict__ Bt,   // tiled [N-tiles] bf16 bits
    const float* __restrict__ bias,          // [N] fp32
    float* __restrict__ C)                   // [M][N] fp32
{
    __shared__ __attribute__((aligned(16))) unsigned short As[4][8192];
    __shared__ __attribute__((aligned(16))) unsigned short Bs[4][8192];

    const int tid = threadIdx.x;
    const int lane = tid & 63, wave = tid >> 6;
    const int wm = wave >> 2, wn = wave & 3;

    // bijective XCD swizzle: 768 wgs = 8 XCDs x 96.
    const int wgid = (blockIdx.x & 7) * 96 + (blockIdx.x >> 3);
    const int bm = wgid & 15;    // 0..15  (M/256)
    const int bn = wgid >> 4;    // 0..47  (N/256)

    // ---- staging: pure linear stream; thread t covers bytes t*16 ----
    const unsigned short* Ag = A + ((size_t)bm << 20) + tid * 8;
    const unsigned short* Bg = Bt + ((size_t)bn << 20) + tid * 8;
    unsigned short* AsW = &As[0][0] + wave * 512;   // wave-uniform dest base
    unsigned short* BsW = &Bs[0][0] + wave * 512;

    // ---- fragment read offset: contiguous, lane*16B within q-block ----
    const int aOff = lane * 8;

    f32x4 acc[8][4];
    const f32x4 zero = {0.f, 0.f, 0.f, 0.f};
#pragma unroll
    for (int i = 0; i < 8; ++i)
#pragma unroll
        for (int j = 0; j < 4; ++j) acc[i][j] = zero;

    // ---- prologue: regions 0,1,2 of A and B; drain first 4 of 12 ----
    STAGE(AsW, Ag, 0, 0);
    STAGE(BsW, Bg, 0, 0);
    STAGE(AsW, Ag, 1, 1);
    STAGE(BsW, Bg, 1, 1);
    STAGE(AsW, Ag, 2, 2);
    STAGE(BsW, Bg, 2, 2);
    VMCNT8();
    BAR();

    bf16x8 afX[4], afY[4], bf0[4], bf1[4];
    LD_A_SET(afX, 0, 0);                 // first phase's operands
    LD_B_SET(bf0, 0);

#pragma unroll 2
    for (int t = 0; t < 64; ++t) {
        const int s0 = (2 * t) & 3, s1 = (2 * t + 1) & 3;
        const int sd1 = (2 * t + 3) & 3, sA = (2 * t + 2) & 3;
        const int R1 = (2 * t + 3 < 128) ? (2 * t + 3) : 127;
        const int R2 = (2 * t + 4 < 128) ? (2 * t + 4) : 127;
        // P1: compute (s0,mh0); prefetch (s0,mh1)
        STAGE(AsW, Ag, sd1, R1);
        BAR();
        LD_A_SET(afY, s0, 1);
        MFMA_SET(afX, bf0, 0);
        BAR();
        // P2: compute (s0,mh1); prefetch (s1,mh0)+B(s1)  [2t+1 just retired]
        STAGE(BsW, Bg, sd1, R1);
        VMCNT8();
        BAR();
        LD_A_SET(afX, s1, 0);
        LD_B_SET(bf1, s1);
        MFMA_SET(afY, bf0, 1);
        BAR();
        // P3: compute (s1,mh0); prefetch (s1,mh1)
        STAGE(AsW, Ag, s0, R2);
        BAR();
        LD_A_SET(afY, s1, 1);
        MFMA_SET(afX, bf1, 0);
        BAR();
        // P4: compute (s1,mh1); prefetch next tile (s0',mh0)+B(s0')
        STAGE(BsW, Bg, s0, R2);
        VMCNT8();                        // retires regions 2t+2 (next s0')
        BAR();
        if (t < 63) {
            LD_A_SET(afX, sA, 0);
            LD_B_SET(bf0, sA);
        }
        MFMA_SET(afY, bf1, 1);
        BAR();
    }

    // ---- epilogue: C/D layout col = lane&15, row = (lane>>4)*4 + r ----
    const int colb = bn * 256 + wn * 64 + (lane & 15);
    const int rowb = bm * 256 + wm * 128 + (lane >> 4) * 4;
    float bj[4];
#pragma unroll
    for (int j = 0; j < 4; ++j) bj[j] = bias[colb + j * 16];
#pragma unroll
    for (int mf = 0; mf < 8; ++mf)
#pragma unroll
        for (int r = 0; r < 4; ++r) {
            const size_t row = (size_t)(rowb + mf * 16 + r);
#pragma unroll
            for (int j = 0; j < 4; ++j)
                C[row * Ndim + colb + j * 16] = acc[mf][j][r] + bj[j];
        }
}

extern "C" void kernel_launch(void* const* d_in, const int* in_sizes, int n_in,
                              void* d_out, int out_size, void* d_ws, size_t ws_size,
                              hipStream_t stream) {
    const float* input   = (const float*)d_in[0];   // [M][K] fp32 (fp16 promoted)
    const int*   qw      = (const int*)d_in[1];     // [K/8][N]
    const int*   qs      = (const int*)d_in[2];     // [G][N/8]
    const float* qsm     = (const float*)d_in[3];   // [G] fp32
    const int*   invperm = (const int*)d_in[4];     // [K]
    const float* bias    = (const float*)d_in[5];   // [N] fp32 (zeros)
    float*       out     = (float*)d_out;           // [M][N] fp32

    unsigned short* Ab = (unsigned short*)d_ws;                      // 32 MiB
    unsigned short* Wt = (unsigned short*)((char*)d_ws + ((size_t)Mdim * Kdim * 2)); // 96 MiB

    permute_convert_a_kernel<<<Mdim / 16, 512, 0, stream>>>(input, invperm, Ab);
    dequant_kernel<<<dim3(Kdim / 64, Ndim / 64), 256, 0, stream>>>(qw, qs, qsm, Wt);
    gemm_bf16_256_kernel<<<dim3((Mdim / 256) * (Ndim / 256)), 512, 0, stream>>>(
        Ab, Wt, bias, out);
}

// Round 7
// 610.850 us; speedup vs baseline: 1.0348x; 1.0188x over previous
//
#include <hip/hip_runtime.h>

#define Mdim 4096
#define Kdim 4096
#define Ndim 12288

typedef __bf16 bf16x8 __attribute__((ext_vector_type(8)));
typedef float f32x4 __attribute__((ext_vector_type(4)));
typedef unsigned short u16x8 __attribute__((ext_vector_type(8)));
typedef int i32x4 __attribute__((ext_vector_type(4)));

__device__ __forceinline__ unsigned short f2bf(float f) {
    unsigned int u = __builtin_bit_cast(unsigned int, f);
    u += 0x7FFFu + ((u >> 16) & 1u);       // RNE
    return (unsigned short)(u >> 16);
}

typedef __attribute__((address_space(1))) void gvoid_t;
typedef __attribute__((address_space(3))) void lvoid_t;
__device__ __forceinline__ void gld16(const void* g, void* l) {
    // 16B per lane, LDS dest = wave-uniform base + lane*16
    __builtin_amdgcn_global_load_lds((gvoid_t*)g, (lvoid_t*)l, 16, 0, 0);
}

// ---------------------------------------------------------------------------
// TILED OPERAND FORMAT (fragment order), shared by writer kernels and GEMM.
// For a 256-row operand tile bx (bm or bn), element (row, k):
//   ks = k>>5 (region, 8192 halves), kk = k&31, q = row>>4 (512-half block),
//   chunk l = (row&15) + 16*(kk>>3)   (16B chunks, MFMA-fragment order)
//   addr_halves = bx*2^20 + ks*8192 + q*512 + l*8 + (kk&7)
// GEMM staging reads 1KB fully-contiguous per wave-instr AND the LDS image
// gives fully-sequential fragment ds_reads (0 bank conflicts, r4-verified).
// ---------------------------------------------------------------------------

// ---------------------------------------------------------------------------
// Kernel 0: A fp32 -> bf16, K-permutation folded in, TILED output (unchanged).
// ---------------------------------------------------------------------------
__global__ __launch_bounds__(512) void permute_convert_a_kernel(
    const float* __restrict__ A, const int* __restrict__ invperm,
    unsigned short* __restrict__ Ab)
{
    __shared__ unsigned short rowbuf[16][4104];   // +16B row pad (bank spread)
    const int tid = threadIdx.x;
    const int m0 = blockIdx.x * 16;
    const int bm = m0 >> 8;
    const int q  = (m0 >> 4) & 15;
#pragma unroll
    for (int c = 0; c < 2; ++c) {
        const int i = (c * 512 + tid) * 4;
        const i32x4 ip = *(const i32x4*)&invperm[i];
        for (int r = 0; r < 16; ++r) {
            const f32x4 v = *(const f32x4*)&A[(size_t)(m0 + r) * Kdim + i];
#pragma unroll
            for (int u = 0; u < 4; ++u) rowbuf[r][ip[u]] = f2bf(v[u]);
        }
    }
    __syncthreads();
    unsigned short* dst = Ab + ((size_t)bm << 20) + q * 512;
    for (int it = 0; it < 16; ++it) {
        const int c = it * 512 + tid;             // 0..8191
        const int ks = c >> 6, c8 = c & 63;
        const u16x8 v = *(const u16x8*)&rowbuf[c8 & 15][ks * 32 + (c8 >> 4) * 8];
        *(u16x8*)&dst[(size_t)ks * 8192 + c8 * 8] = v;   // 1KB contig / 64 thr
    }
}

// ---------------------------------------------------------------------------
// Kernel 1: dequant in natural k-order, TILED output (unchanged).
// ---------------------------------------------------------------------------
__global__ __launch_bounds__(256) void dequant_kernel(
    const int* __restrict__ qw,              // [K/8][N]
    const int* __restrict__ qs,              // [G][N/8]
    const float* __restrict__ qsm,           // [G] fp32
    unsigned short* __restrict__ Wt)         // tiled bf16 bits
{
    __shared__ unsigned short tile[64 * 72];
    const int k0 = blockIdx.x * 64;
    const int n0 = blockIdx.y * 64;
    const int g = k0 >> 7;
    const int tid = threadIdx.x;
    const int n_l = tid & 63;
    const int kb_l = tid >> 6;
    const int n = n0 + n_l;
    const int sw = qs[g * (Ndim / 8) + (n >> 3)];
    const int sc = (sw >> ((n & 7) * 4)) & 0xF;
    const float scale = (float)((sc + 1) * (sc + 1)) * qsm[g];
#pragma unroll
    for (int ii = 0; ii < 2; ++ii) {
        const int kb = kb_l + ii * 4;
        const int w = qw[(size_t)(k0 / 8 + kb) * Ndim + n];
        u16x8 o;
#pragma unroll
        for (int u = 0; u < 8; ++u)
            o[u] = f2bf((float)(((w >> (4 * u)) & 0xF) - 8) * scale);
        *(u16x8*)&tile[n_l * 72 + kb * 8] = o;
    }
    __syncthreads();
    const int bn  = n0 >> 8;
    const int q0  = (n0 >> 4) & 15;
    const int ks0 = k0 >> 5;
    unsigned short* dst = Wt + ((size_t)bn << 20) + (size_t)ks0 * 8192 + q0 * 512;
#pragma unroll
    for (int cc = 0; cc < 2; ++cc) {
        const int c  = cc * 256 + tid;            // 0..511
        const int ksl = c >> 8;                   // 0..1
        const int cq  = (c >> 6) & 3;             // q-block within our 64n
        const int c8  = c & 63;
        const u16x8 v = *(const u16x8*)
            &tile[(cq * 16 + (c8 & 15)) * 72 + ksl * 32 + (c8 >> 4) * 8];
        *(u16x8*)&dst[(size_t)ksl * 8192 + cq * 512 + c8 * 8] = v;
    }
}

// ---------------------------------------------------------------------------
// Kernel 2: bf16 GEMM, 256x256 tile, BK=64, 8 waves, pre-tiled operands.
// Round-7: r4's schedule with the m201 PHASE ORDER: each phase is
//   { ds_reads (this phase's frags) ; STAGE ; [vmcnt8] ; BAR ;
//     sched_barrier(0) ; setprio(1) 16xMFMA setprio(0) ; BAR }
// Reads sit BEFORE the barrier: pinned there (ds_read can't sink past the
// asm memory-clobber barrier), so LDS service overlaps barrier-wait and,
// via progressive lgkm waits, the MFMA cluster.  sched_barrier(0) stops the
// scheduler hoisting MFMAs above the barrier (rule-18 analog).
// Hazards (re-derived for read-at-top order):
//   read slots: s0 read P1/P2 (region 2t, retired by t-1 P4 vmcnt8, 2 bars
//   earlier); s1 read P3/P4 (region 2t+1, retired by THIS tile's P2 vmcnt8,
//   2 bars earlier).  STAGE targets: sd1=(2t+3)&3 disjoint from {s0,s1};
//   P3/P4 re-stage slot s0 -- its readers (P1/P2) drained their ds_reads
//   before their own MFMA (lgkm) which precedes the barrier the staging
//   wave must pass.  vmcnt FIFO identical to r4 (8 glds/tile in, 8 out).
//   Tail t=63: clamped stages hit dead slots (verified: reads use slots
//   2,3; clamps write slots 1,2 after their last reads).
// ---------------------------------------------------------------------------
#define BAR()    asm volatile("s_barrier" ::: "memory")
#define VMCNT8() asm volatile("s_waitcnt vmcnt(8)" ::: "memory")
#define SCHED0() __builtin_amdgcn_sched_barrier(0)

#define STAGE(dstW, src, slot, R) do {                                      \
    gld16((src) + (size_t)(R) * 8192, (dstW) + (slot) * 8192);              \
    gld16((src) + (size_t)(R) * 8192 + 4096,                                \
          (dstW) + (slot) * 8192 + 4096); } while (0)

#define LD_A(slot, mh) do {                                                 \
    const unsigned short* p_ = &As[slot][wm * 4096 + (mh) * 2048 + aOff];   \
    af[0] = *(const bf16x8*)(p_);                                           \
    af[1] = *(const bf16x8*)(p_ + 512);                                     \
    af[2] = *(const bf16x8*)(p_ + 1024);                                    \
    af[3] = *(const bf16x8*)(p_ + 1536); } while (0)

#define LD_B(slot) do {                                                     \
    const unsigned short* p_ = &Bs[slot][wn * 2048 + aOff];                 \
    bfr[0] = *(const bf16x8*)(p_);                                          \
    bfr[1] = *(const bf16x8*)(p_ + 512);                                    \
    bfr[2] = *(const bf16x8*)(p_ + 1024);                                   \
    bfr[3] = *(const bf16x8*)(p_ + 1536); } while (0)

#define MFMA_HALF(mh) do {                                                  \
    __builtin_amdgcn_s_setprio(1);                                          \
    _Pragma("unroll")                                                       \
    for (int i_ = 0; i_ < 4; ++i_)                                          \
      _Pragma("unroll")                                                     \
      for (int j_ = 0; j_ < 4; ++j_)                                        \
        acc[(mh) * 4 + i_][j_] = __builtin_amdgcn_mfma_f32_16x16x32_bf16(   \
            af[i_], bfr[j_], acc[(mh) * 4 + i_][j_], 0, 0, 0);              \
    __builtin_amdgcn_s_setprio(0); } while (0)

__global__ __launch_bounds__(512, 2) void gemm_bf16_256_kernel(
    const unsigned short* __restrict__ A,    // tiled [M-tiles] bf16 bits
    const unsigned short* __restrict__ Bt,   // tiled [N-tiles] bf16 bits
    const float* __restrict__ bias,          // [N] fp32
    float* __restrict__ C)                   // [M][N] fp32
{
    __shared__ __attribute__((aligned(16))) unsigned short As[4][8192];
    __shared__ __attribute__((aligned(16))) unsigned short Bs[4][8192];

    const int tid = threadIdx.x;
    const int lane = tid & 63, wave = tid >> 6;
    const int wm = wave >> 2, wn = wave & 3;

    // bijective XCD swizzle: 768 wgs = 8 XCDs x 96.
    const int wgid = (blockIdx.x & 7) * 96 + (blockIdx.x >> 3);
    const int bm = wgid & 15;    // 0..15  (M/256)
    const int bn = wgid >> 4;    // 0..47  (N/256)

    // ---- staging: pure linear stream; thread t covers bytes t*16 ----
    const unsigned short* Ag = A + ((size_t)bm << 20) + tid * 8;
    const unsigned short* Bg = Bt + ((size_t)bn << 20) + tid * 8;
    unsigned short* AsW = &As[0][0] + wave * 512;   // wave-uniform dest base
    unsigned short* BsW = &Bs[0][0] + wave * 512;

    // ---- fragment read offset: contiguous, lane*16B within q-block ----
    const int aOff = lane * 8;

    f32x4 acc[8][4];
    const f32x4 zero = {0.f, 0.f, 0.f, 0.f};
#pragma unroll
    for (int i = 0; i < 8; ++i)
#pragma unroll
        for (int j = 0; j < 4; ++j) acc[i][j] = zero;

    // ---- prologue: regions 0,1,2 of A and B; drain first 4 of 12 ----
    STAGE(AsW, Ag, 0, 0);
    STAGE(BsW, Bg, 0, 0);
    STAGE(AsW, Ag, 1, 1);
    STAGE(BsW, Bg, 1, 1);
    STAGE(AsW, Ag, 2, 2);
    STAGE(BsW, Bg, 2, 2);
    VMCNT8();
    BAR();

    bf16x8 af[4], bfr[4];
#pragma unroll 2
    for (int t = 0; t < 64; ++t) {
        const int s0 = (2 * t) & 3, s1 = (2 * t + 1) & 3;
        const int sd1 = (2 * t + 3) & 3;
        const int R1 = (2 * t + 3 < 128) ? (2 * t + 3) : 127;
        const int R2 = (2 * t + 4 < 128) ? (2 * t + 4) : 127;
        // P1: reads (s0,mh0)+B(s0) | stage A(R1) | bar | 16 MFMA | bar
        LD_A(s0, 0);
        LD_B(s0);
        STAGE(AsW, Ag, sd1, R1);
        BAR();
        SCHED0();
        MFMA_HALF(0);
        BAR();
        // P2: reads (s0,mh1) | stage B(R1) | vmcnt8 | bar | 16 MFMA | bar
        LD_A(s0, 1);
        STAGE(BsW, Bg, sd1, R1);
        VMCNT8();                      // retires region 2t+1 (read at P3)
        BAR();
        SCHED0();
        MFMA_HALF(1);
        BAR();
        // P3: reads (s1,mh0)+B(s1) | stage A(R2) | bar | 16 MFMA | bar
        LD_A(s1, 0);
        LD_B(s1);
        STAGE(AsW, Ag, s0, R2);        // s0 slot: readers drained in P1/P2
        BAR();
        SCHED0();
        MFMA_HALF(0);
        BAR();
        // P4: reads (s1,mh1) | stage B(R2) | vmcnt8 | bar | 16 MFMA | bar
        LD_A(s1, 1);
        STAGE(BsW, Bg, s0, R2);
        VMCNT8();                      // retires region 2t+2 (read at t+1 P1)
        BAR();
        SCHED0();
        MFMA_HALF(1);
        BAR();
    }

    // ---- epilogue: C/D layout col = lane&15, row = (lane>>4)*4 + r ----
    const int colb = bn * 256 + wn * 64 + (lane & 15);
    const int rowb = bm * 256 + wm * 128 + (lane >> 4) * 4;
    float bj[4];
#pragma unroll
    for (int j = 0; j < 4; ++j) bj[j] = bias[colb + j * 16];
#pragma unroll
    for (int mf = 0; mf < 8; ++mf)
#pragma unroll
        for (int r = 0; r < 4; ++r) {
            const size_t row = (size_t)(rowb + mf * 16 + r);
#pragma unroll
            for (int j = 0; j < 4; ++j)
                C[row * Ndim + colb + j * 16] = acc[mf][j][r] + bj[j];
        }
}

extern "C" void kernel_launch(void* const* d_in, const int* in_sizes, int n_in,
                              void* d_out, int out_size, void* d_ws, size_t ws_size,
                              hipStream_t stream) {
    const float* input   = (const float*)d_in[0];   // [M][K] fp32 (fp16 promoted)
    const int*   qw      = (const int*)d_in[1];     // [K/8][N]
    const int*   qs      = (const int*)d_in[2];     // [G][N/8]
    const float* qsm     = (const float*)d_in[3];   // [G] fp32
    const int*   invperm = (const int*)d_in[4];     // [K]
    const float* bias    = (const float*)d_in[5];   // [N] fp32 (zeros)
    float*       out     = (float*)d_out;           // [M][N] fp32

    unsigned short* Ab = (unsigned short*)d_ws;                      // 32 MiB
    unsigned short* Wt = (unsigned short*)((char*)d_ws + ((size_t)Mdim * Kdim * 2)); // 96 MiB

    permute_convert_a_kernel<<<Mdim / 16, 512, 0, stream>>>(input, invperm, Ab);
    dequant_kernel<<<dim3(Kdim / 64, Ndim / 64), 256, 0, stream>>>(qw, qs, qsm, Wt);
    gemm_bf16_256_kernel<<<dim3((Mdim / 256) * (Ndim / 256)), 512, 0, stream>>>(
        Ab, Wt, bias, out);
}